// Round 7
// baseline (224.010 us; speedup 1.0000x reference)
//
#include <hip/hip_runtime.h>

#define NB 128
#define NN 50000
#define NE 300000
#define ND 256
#define NP 8

typedef __attribute__((ext_vector_type(4))) float f32x4;
typedef __attribute__((ext_vector_type(8))) short s16x8;
typedef __attribute__((ext_vector_type(4))) short s16x4;

__device__ __forceinline__ unsigned short bf16rtn(float f) {
    unsigned int u = __float_as_uint(f);
    unsigned int r = (u + 0x7fffu + ((u >> 16) & 1u)) >> 16;
    return (unsigned short)r;
}

// swizzled LDS byte offset for [row][256 bf16] tiles (row stride 512B),
// XOR bits 4-6 with row&7 -> conflict-free ds_read_b128 (guide G4 pattern)
__device__ __forceinline__ int swz(int row, int kbyte) {
    return row * 512 + (kbyte ^ ((row & 7) << 4));
}

__device__ __forceinline__ float eluf(float x) {
    return x > 0.f ? x : __expf(x) - 1.f;
}

// sum across the 16 lanes of a DPP row (VALU-only butterfly, no LDS).
__device__ __forceinline__ float rowsum16(float x) {
    int t;
    t = __builtin_amdgcn_update_dpp(0, __float_as_int(x), 0x121, 0xf, 0xf, true);
    x += __int_as_float(t);
    t = __builtin_amdgcn_update_dpp(0, __float_as_int(x), 0x122, 0xf, 0xf, true);
    x += __int_as_float(t);
    t = __builtin_amdgcn_update_dpp(0, __float_as_int(x), 0x124, 0xf, 0xf, true);
    x += __int_as_float(t);
    t = __builtin_amdgcn_update_dpp(0, __float_as_int(x), 0x128, 0xf, 0xf, true);
    x += __int_as_float(t);
    return x;
}

// ---- staging split (T14): load f32 tile rows into regs ... pack+write LDS ----
template <typename G>
__device__ __forceinline__ void stage_load(f32x4 a[4], const float* base_row0,
                                           int tid, G valid_row) {
    int r = tid >> 4;
    int i = tid & 15;
    bool v = valid_row(r);
    const float* p = base_row0 + (size_t)r * ND + i * 4;
#pragma unroll
    for (int j = 0; j < 4; ++j) {
        f32x4 z = {0.f, 0.f, 0.f, 0.f};
        a[j] = v ? *(const f32x4*)(p + 64 * j) : z;
    }
}

__device__ __forceinline__ void stage_write(char* Al, const f32x4 a[4], int tid) {
    int r = tid >> 4;
    int i = tid & 15;
#pragma unroll
    for (int j = 0; j < 4; ++j) {
        s16x4 v;
        v[0] = (short)bf16rtn(a[j][0]); v[1] = (short)bf16rtn(a[j][1]);
        v[2] = (short)bf16rtn(a[j][2]); v[3] = (short)bf16rtn(a[j][3]);
        *(s16x4*)(Al + r * 512 + (((i << 3) + (j << 7)) ^ ((r & 7) << 4))) = v;
    }
}

// ---------------- segment boundaries + rel_logits zeroing ------------------
// (folded zeroing here to avoid the slow rocclr fillBuffer path in-graph)
__global__ void k_starts(const int* __restrict__ idx, int* __restrict__ starts,
                         float* __restrict__ rel_logits) {
    int n = blockIdx.x * blockDim.x + threadIdx.x;
    if (n >= NN) return;
    rel_logits[n] = 0.f;
    int cur = idx[n];
    int prev = (n == 0) ? -1 : idx[n - 1];
    for (int b2 = prev + 1; b2 <= cur; ++b2) starts[b2] = n;
    if (n == NN - 1)
        for (int b2 = cur + 1; b2 <= NB; ++b2) starts[b2] = NN;
}

// ---------------- W_edge f32 -> bf16 --------------------------------------
__global__ void k_wedge_bf16(const float* __restrict__ w, unsigned short* __restrict__ o) {
    int i = (blockIdx.x * 256 + threadIdx.x) * 4;
    f32x4 v = *(const f32x4*)(w + i);
    o[i + 0] = bf16rtn(v[0]); o[i + 1] = bf16rtn(v[1]);
    o[i + 2] = bf16rtn(v[2]); o[i + 3] = bf16rtn(v[3]);
}

// ---------------- W_eff[b] = sum_p sim[b,p] * W_p  (f32 -> bf16) ----------
__global__ __launch_bounds__(256) void k_weff(
    const float* __restrict__ sim, const float* __restrict__ Wp,
    unsigned short* __restrict__ Weff)
{
    int chunk = blockIdx.x * 256 + threadIdx.x;
    int off = chunk * 8;
    float wp[NP][8];
#pragma unroll
    for (int p = 0; p < NP; ++p) {
        const float* src = Wp + (size_t)p * ND * ND + off;
        f32x4 w0 = *(const f32x4*)src;
        f32x4 w1 = *(const f32x4*)(src + 4);
        wp[p][0] = w0[0]; wp[p][1] = w0[1]; wp[p][2] = w0[2]; wp[p][3] = w0[3];
        wp[p][4] = w1[0]; wp[p][5] = w1[1]; wp[p][6] = w1[2]; wp[p][7] = w1[3];
    }
    int b0 = blockIdx.y * 16;
    for (int bb = 0; bb < 16; ++bb) {
        int b = b0 + bb;
        float g[8] = {0.f, 0.f, 0.f, 0.f, 0.f, 0.f, 0.f, 0.f};
#pragma unroll
        for (int p = 0; p < NP; ++p) {
            float s = sim[b * NP + p];
#pragma unroll
            for (int j = 0; j < 8; ++j) g[j] += s * wp[p][j];
        }
        s16x8 v;
#pragma unroll
        for (int j = 0; j < 8; ++j) v[j] = (short)bf16rtn(g[j]);
        *(s16x8*)(Weff + (size_t)b * ND * ND + off) = v;
    }
}

// ---------------- edge kernel (persistent, double-buffered) ----------------
// grid = 512. Block streams 64-edge tiles with stride 512*64.
// 16 waves = 2 rowquads x 8 colquads; per wave 2rg x 2cg, bfrag persistent.
// Pipeline: prefetch instr gathers (rg0) -> issue tile t+1 global loads ->
// MFMA tile t -> issue rg1 gathers -> epilogue -> barrier -> atomic(t) +
// pack/write(t+1) -> barrier. instr is L2-resident (131KB): gathers cost
// ~200cy each; issuing them pre-MFMA hides that under compute.
// launch_bounds(1024,4): 1 block/CU, <=128 combined regs -- no spill.
__global__ __launch_bounds__(1024, 4) void k_edges(
    const float* __restrict__ instr, const float* __restrict__ dist,
    const float* __restrict__ eattrs, const unsigned short* __restrict__ Wbf,
    const float* __restrict__ wrs, const int* __restrict__ ebidx,
    const int* __restrict__ eidx, float* __restrict__ rel_logits)
{
    __shared__ char Al[2][32768];
    __shared__ float part[8][64];
    __shared__ int ebs[2][64];
    __shared__ int dsts[2][64];
    __shared__ float dscs[2][64];

    int tid = threadIdx.x;
    int lane = tid & 63;
    int wave = tid >> 6;
    int l15 = lane & 15;
    int q = lane >> 4;
    int rq = wave >> 3;
    int cq = wave & 7;

    // persistent B fragments: this wave's 2x16-col slice of W_edge
    s16x8 bfrag[2][8];
#pragma unroll
    for (int cg = 0; cg < 2; ++cg)
#pragma unroll
        for (int kk = 0; kk < 8; ++kk)
            bfrag[cg][kk] = *(const s16x8*)(Wbf + (size_t)(cq * 32 + cg * 16 + l15) * ND + kk * 32 + q * 8);
    float wv0 = wrs[cq * 32 + l15];
    float wv1 = wrs[cq * 32 + 16 + l15];

    // prologue: stage first tile
    int e0 = blockIdx.x * 64;
    f32x4 sreg[4];
    int mb = 0, md = 0; float ms = 0.f;
    stage_load(sreg, eattrs + (size_t)e0 * ND, tid,
               [&](int r) { return e0 + r < NE; });
    if (tid < 64) {
        int e = e0 + tid;
        if (e < NE) { mb = ebidx[e]; md = eidx[NE + e]; ms = dist[eidx[e]]; }
    }
    stage_write(Al[0], sreg, tid);
    if (tid < 64) { ebs[0][tid] = mb; dsts[0][tid] = md; dscs[0][tid] = ms; }
    __syncthreads();

    int cur = 0;
    while (true) {
        // ---- prefetch instr gathers for current tile, rg=0 (hidden by MFMA)
        float pfa[4], pfb[4];
#pragma unroll
        for (int reg = 0; reg < 4; ++reg) {
            int rl = rq * 32 + 4 * q + reg;
            const float* irow = instr + (size_t)ebs[cur][rl] * ND;
            pfa[reg] = irow[cq * 32 + l15];
            pfb[reg] = irow[cq * 32 + 16 + l15];
        }

        int e0n = e0 + 512 * 64;
        bool hn = e0n < NE;
        if (hn) {   // issue next tile's loads early (hide under compute)
            stage_load(sreg, eattrs + (size_t)e0n * ND, tid,
                       [&](int r) { return e0n + r < NE; });
            if (tid < 64) {
                int e = e0n + tid;
                if (e < NE) { mb = ebidx[e]; md = eidx[NE + e]; ms = dist[eidx[e]]; }
                else { mb = 0; md = 0; ms = 0.f; }
            }
        }

        // ---- MFMA on Al[cur] ----
        f32x4 acc[2][2] = {};
#pragma unroll
        for (int rg = 0; rg < 2; ++rg) {
            int arow = rq * 32 + rg * 16 + l15;
#pragma unroll
            for (int kk = 0; kk < 8; ++kk) {
                s16x8 a = *(const s16x8*)(Al[cur] + swz(arow, kk * 64 + q * 16));
                acc[rg][0] = __builtin_amdgcn_mfma_f32_16x16x32_bf16(a, bfrag[0][kk], acc[rg][0], 0, 0, 0);
                acc[rg][1] = __builtin_amdgcn_mfma_f32_16x16x32_bf16(a, bfrag[1][kk], acc[rg][1], 0, 0, 0);
            }
        }

        // ---- issue rg=1 gathers, then process rg=0 (hides rg1 L2 latency) --
        float pfc[4], pfd[4];
#pragma unroll
        for (int reg = 0; reg < 4; ++reg) {
            int rl = rq * 32 + 16 + 4 * q + reg;
            const float* irow = instr + (size_t)ebs[cur][rl] * ND;
            pfc[reg] = irow[cq * 32 + l15];
            pfd[reg] = irow[cq * 32 + 16 + l15];
        }
#pragma unroll
        for (int reg = 0; reg < 4; ++reg) {
            int rl = rq * 32 + 4 * q + reg;
            float p = rowsum16(wv0 * eluf(pfa[reg] * acc[0][0][reg])
                             + wv1 * eluf(pfb[reg] * acc[0][1][reg]));
            if (l15 == 0) part[cq][rl] = p;
        }
#pragma unroll
        for (int reg = 0; reg < 4; ++reg) {
            int rl = rq * 32 + 16 + 4 * q + reg;
            float p = rowsum16(wv0 * eluf(pfc[reg] * acc[1][0][reg])
                             + wv1 * eluf(pfd[reg] * acc[1][1][reg]));
            if (l15 == 0) part[cq][rl] = p;
        }
        __syncthreads();

        if (tid < 64 && e0 + tid < NE) {
            float s = 0.f;
#pragma unroll
            for (int w = 0; w < 8; ++w) s += part[w][tid];
            atomicAdd(&rel_logits[dsts[cur][tid]], dscs[cur][tid] * s);
        }
        if (hn) {
            stage_write(Al[cur ^ 1], sreg, tid);
            if (tid < 64) { ebs[cur ^ 1][tid] = mb; dsts[cur ^ 1][tid] = md; dscs[cur ^ 1][tid] = ms; }
        }
        __syncthreads();
        if (!hn) break;
        cur ^= 1; e0 = e0n;
    }
}

// ---------------- node kernel (same template, plain store) ----------------
// grid = NB*4: (b = idx>>2, qb = idx&3), tiles stride 4, double-buffered.
__global__ __launch_bounds__(1024, 4) void k_nodes(
    const float* __restrict__ instr, const unsigned short* __restrict__ Weff,
    const float* __restrict__ attrs, const float* __restrict__ wns,
    const int* __restrict__ starts, float* __restrict__ state_logits)
{
    __shared__ char Al[2][32768];
    __shared__ float part[8][64];

    int b = blockIdx.x >> 2;
    int qb = blockIdx.x & 3;
    int s0 = starts[b], s1 = starts[b + 1];
    int nt = (s1 - s0 + 63) >> 6;
    if (qb >= nt) return;

    int tid = threadIdx.x;
    int lane = tid & 63;
    int wave = tid >> 6;
    int l15 = lane & 15;
    int q = lane >> 4;
    int rq = wave >> 3;
    int cq = wave & 7;

    const unsigned short* Wb = Weff + (size_t)b * ND * ND;
    s16x8 bfrag[2][8];
#pragma unroll
    for (int cg = 0; cg < 2; ++cg)
#pragma unroll
        for (int kk = 0; kk < 8; ++kk)
            bfrag[cg][kk] = *(const s16x8*)(Wb + (size_t)(cq * 32 + cg * 16 + l15) * ND + kk * 32 + q * 8);
    float iv0 = instr[b * ND + cq * 32 + l15];
    float iv1 = instr[b * ND + cq * 32 + 16 + l15];
    float wv0 = wns[cq * 32 + l15];
    float wv1 = wns[cq * 32 + 16 + l15];

    int ti = qb;
    f32x4 sreg[4];
    {
        int node0 = s0 + ti * 64;
        stage_load(sreg, attrs + (size_t)node0 * ND, tid,
                   [&](int r) { return node0 + r < s1; });
        stage_write(Al[0], sreg, tid);
    }
    __syncthreads();

    int cur = 0;
    while (true) {
        int node0 = s0 + ti * 64;
        int tin = ti + 4;
        bool hn = tin < nt;
        if (hn) {
            int n0n = s0 + tin * 64;
            stage_load(sreg, attrs + (size_t)n0n * ND, tid,
                       [&](int r) { return n0n + r < s1; });
        }

        f32x4 acc[2][2] = {};
#pragma unroll
        for (int rg = 0; rg < 2; ++rg) {
            int arow = rq * 32 + rg * 16 + l15;
#pragma unroll
            for (int kk = 0; kk < 8; ++kk) {
                s16x8 a = *(const s16x8*)(Al[cur] + swz(arow, kk * 64 + q * 16));
                acc[rg][0] = __builtin_amdgcn_mfma_f32_16x16x32_bf16(a, bfrag[0][kk], acc[rg][0], 0, 0, 0);
                acc[rg][1] = __builtin_amdgcn_mfma_f32_16x16x32_bf16(a, bfrag[1][kk], acc[rg][1], 0, 0, 0);
            }
        }

#pragma unroll
        for (int rg = 0; rg < 2; ++rg)
#pragma unroll
            for (int reg = 0; reg < 4; ++reg) {
                int rl = rq * 32 + rg * 16 + 4 * q + reg;
                float p = rowsum16(wv0 * eluf(iv0 * acc[rg][0][reg])
                                 + wv1 * eluf(iv1 * acc[rg][1][reg]));
                if (l15 == 0) part[cq][rl] = p;
            }
        __syncthreads();

        if (tid < 64) {
            int node = node0 + tid;
            if (node < s1) {
                float s = 0.f;
#pragma unroll
                for (int w = 0; w < 8; ++w) s += part[w][tid];
                state_logits[node] = s;
            }
        }
        if (hn) stage_write(Al[cur ^ 1], sreg, tid);
        __syncthreads();
        if (!hn) break;
        cur ^= 1; ti = tin;
    }
}

// ---------------- per-graph softmaxes + final mix -------------------------
__global__ __launch_bounds__(256) void k_softmax_mix(
    const float* __restrict__ state_l, const float* __restrict__ rel_l,
    const int* __restrict__ starts, const float* __restrict__ relsim,
    float* __restrict__ out)
{
    __shared__ float wms[4], wmr[4], wss[4], wsr[4];
    int b = blockIdx.x;
    int s0 = starts[b], s1 = starts[b + 1];
    if (s1 <= s0) return;
    int tid = threadIdx.x, lane = tid & 63, wave = tid >> 6;

    float ms = -3.4e38f, mr = -3.4e38f;
    for (int n = s0 + tid; n < s1; n += 256) {
        ms = fmaxf(ms, state_l[n]);
        mr = fmaxf(mr, rel_l[n]);
    }
#pragma unroll
    for (int m = 1; m < 64; m <<= 1) {
        ms = fmaxf(ms, __shfl_xor(ms, m, 64));
        mr = fmaxf(mr, __shfl_xor(mr, m, 64));
    }
    if (lane == 0) { wms[wave] = ms; wmr[wave] = mr; }
    __syncthreads();
    ms = fmaxf(fmaxf(wms[0], wms[1]), fmaxf(wms[2], wms[3]));
    mr = fmaxf(fmaxf(wmr[0], wmr[1]), fmaxf(wmr[2], wmr[3]));

    float ss = 0.f, sr = 0.f;
    for (int n = s0 + tid; n < s1; n += 256) {
        ss += __expf(state_l[n] - ms);
        sr += __expf(rel_l[n] - mr);
    }
#pragma unroll
    for (int m = 1; m < 64; m <<= 1) {
        ss += __shfl_xor(ss, m, 64);
        sr += __shfl_xor(sr, m, 64);
    }
    if (lane == 0) { wss[wave] = ss; wsr[wave] = sr; }
    __syncthreads();
    ss = wss[0] + wss[1] + wss[2] + wss[3];
    sr = wsr[0] + wsr[1] + wsr[2] + wsr[3];

    float rb = relsim[b];
    float iss = 1.f / ss, isr = 1.f / sr;
    for (int n = s0 + tid; n < s1; n += 256) {
        out[n] = rb * __expf(rel_l[n] - mr) * isr
               + (1.f - rb) * __expf(state_l[n] - ms) * iss;
    }
}

extern "C" void kernel_launch(void* const* d_in, const int* in_sizes, int n_in,
                              void* d_out, int out_size, void* d_ws, size_t ws_size,
                              hipStream_t stream) {
    const float* instr  = (const float*)d_in[0];
    const float* dist   = (const float*)d_in[1];
    const float* sim    = (const float*)d_in[2];
    const float* relsim = (const float*)d_in[3];
    const float* nattr  = (const float*)d_in[4];
    const float* eattr  = (const float*)d_in[5];
    const float* Wp     = (const float*)d_in[6];
    const float* We     = (const float*)d_in[7];
    const float* wns    = (const float*)d_in[8];
    const float* wrs    = (const float*)d_in[9];
    const int* nidx     = (const int*)d_in[10];
    const int* ebidx    = (const int*)d_in[11];
    const int* eidx     = (const int*)d_in[12];
    float* out = (float*)d_out;

    char* ws = (char*)d_ws;
    float* rel_logits   = (float*)ws;                      // NN f @ 0
    float* state_logits = rel_logits + NN;                 // NN f @ 200000
    int* starts         = (int*)(ws + 400000);             // B+1 ints
    unsigned short* Wbf = (unsigned short*)(ws + 400640);  // 256*256 bf16
    unsigned short* Weff= (unsigned short*)(ws + 532480);  // 128*256*256 bf16 (16MB)

    k_wedge_bf16<<<64, 256, 0, stream>>>(We, Wbf);
    k_weff<<<dim3(32, 8), 256, 0, stream>>>(sim, Wp, Weff);
    k_starts<<<(NN + 255) / 256, 256, 0, stream>>>(nidx, starts, rel_logits);
    k_edges<<<512, 1024, 0, stream>>>(instr, dist, eattr, Wbf, wrs,
                                      ebidx, eidx, rel_logits);
    k_nodes<<<NB * 4, 1024, 0, stream>>>(instr, Weff, nattr, wns, starts,
                                         state_logits);
    k_softmax_mix<<<NB, 256, 0, stream>>>(state_logits, rel_logits, starts,
                                          relsim, out);
}

// Round 8
// 193.318 us; speedup vs baseline: 1.1588x; 1.1588x over previous
//
#include <hip/hip_runtime.h>

#define NB 128
#define NN 50000
#define NE 300000
#define ND 256
#define NP 8

typedef __attribute__((ext_vector_type(4))) float f32x4;
typedef __attribute__((ext_vector_type(8))) short s16x8;
typedef __attribute__((ext_vector_type(4))) short s16x4;

__device__ __forceinline__ unsigned short bf16rtn(float f) {
    unsigned int u = __float_as_uint(f);
    unsigned int r = (u + 0x7fffu + ((u >> 16) & 1u)) >> 16;
    return (unsigned short)r;
}

// swizzled LDS byte offset for [row][256 bf16] tiles (row stride 512B),
// XOR bits 4-6 with row&7 -> conflict-free ds_read_b128 (guide G4 pattern)
__device__ __forceinline__ int swz(int row, int kbyte) {
    return row * 512 + (kbyte ^ ((row & 7) << 4));
}

__device__ __forceinline__ float eluf(float x) {
    return x > 0.f ? x : __expf(x) - 1.f;
}

// sum across the 16 lanes of a DPP row (VALU-only butterfly, no LDS).
__device__ __forceinline__ float rowsum16(float x) {
    int t;
    t = __builtin_amdgcn_update_dpp(0, __float_as_int(x), 0x121, 0xf, 0xf, true);
    x += __int_as_float(t);
    t = __builtin_amdgcn_update_dpp(0, __float_as_int(x), 0x122, 0xf, 0xf, true);
    x += __int_as_float(t);
    t = __builtin_amdgcn_update_dpp(0, __float_as_int(x), 0x124, 0xf, 0xf, true);
    x += __int_as_float(t);
    t = __builtin_amdgcn_update_dpp(0, __float_as_int(x), 0x128, 0xf, 0xf, true);
    x += __int_as_float(t);
    return x;
}

// ---- staging: 32-row x 256-col f32 tile; 512 threads -> row tid>>4,
// col-chunk tid&15 (4 floats), 4 strided chunks. Load to regs early,
// pack+ds_write late (T14 split).
template <typename G>
__device__ __forceinline__ void stage_load(f32x4 a[4], const float* base_row0,
                                           int tid, G valid_row) {
    int r = tid >> 4;
    int i = tid & 15;
    bool v = valid_row(r);
    const float* p = base_row0 + (size_t)r * ND + i * 4;
#pragma unroll
    for (int j = 0; j < 4; ++j) {
        f32x4 z = {0.f, 0.f, 0.f, 0.f};
        a[j] = v ? *(const f32x4*)(p + 64 * j) : z;
    }
}

__device__ __forceinline__ void stage_write(char* Al, const f32x4 a[4], int tid) {
    int r = tid >> 4;
    int i = tid & 15;
#pragma unroll
    for (int j = 0; j < 4; ++j) {
        s16x4 v;
        v[0] = (short)bf16rtn(a[j][0]); v[1] = (short)bf16rtn(a[j][1]);
        v[2] = (short)bf16rtn(a[j][2]); v[3] = (short)bf16rtn(a[j][3]);
        *(s16x4*)(Al + r * 512 + (((i << 3) + (j << 7)) ^ ((r & 7) << 4))) = v;
    }
}

// ---------------- segment boundaries + rel_logits zeroing ------------------
__global__ void k_starts(const int* __restrict__ idx, int* __restrict__ starts,
                         float* __restrict__ rel_logits) {
    int n = blockIdx.x * blockDim.x + threadIdx.x;
    if (n >= NN) return;
    rel_logits[n] = 0.f;
    int cur = idx[n];
    int prev = (n == 0) ? -1 : idx[n - 1];
    for (int b2 = prev + 1; b2 <= cur; ++b2) starts[b2] = n;
    if (n == NN - 1)
        for (int b2 = cur + 1; b2 <= NB; ++b2) starts[b2] = NN;
}

// ---------------- W_edge f32 -> bf16 --------------------------------------
__global__ void k_wedge_bf16(const float* __restrict__ w, unsigned short* __restrict__ o) {
    int i = (blockIdx.x * 256 + threadIdx.x) * 4;
    f32x4 v = *(const f32x4*)(w + i);
    o[i + 0] = bf16rtn(v[0]); o[i + 1] = bf16rtn(v[1]);
    o[i + 2] = bf16rtn(v[2]); o[i + 3] = bf16rtn(v[3]);
}

// ---------------- W_eff[b] = sum_p sim[b,p] * W_p  (f32 -> bf16) ----------
__global__ __launch_bounds__(256) void k_weff(
    const float* __restrict__ sim, const float* __restrict__ Wp,
    unsigned short* __restrict__ Weff)
{
    int chunk = blockIdx.x * 256 + threadIdx.x;
    int off = chunk * 8;
    float wp[NP][8];
#pragma unroll
    for (int p = 0; p < NP; ++p) {
        const float* src = Wp + (size_t)p * ND * ND + off;
        f32x4 w0 = *(const f32x4*)src;
        f32x4 w1 = *(const f32x4*)(src + 4);
        wp[p][0] = w0[0]; wp[p][1] = w0[1]; wp[p][2] = w0[2]; wp[p][3] = w0[3];
        wp[p][4] = w1[0]; wp[p][5] = w1[1]; wp[p][6] = w1[2]; wp[p][7] = w1[3];
    }
    int b0 = blockIdx.y * 16;
    for (int bb = 0; bb < 16; ++bb) {
        int b = b0 + bb;
        float g[8] = {0.f, 0.f, 0.f, 0.f, 0.f, 0.f, 0.f, 0.f};
#pragma unroll
        for (int p = 0; p < NP; ++p) {
            float s = sim[b * NP + p];
#pragma unroll
            for (int j = 0; j < 8; ++j) g[j] += s * wp[p][j];
        }
        s16x8 v;
#pragma unroll
        for (int j = 0; j < 8; ++j) v[j] = (short)bf16rtn(g[j]);
        *(s16x8*)(Weff + (size_t)b * ND * ND + off) = v;
    }
}

// ---------------- edge kernel (persistent, double-buffered, 2 blocks/CU) ---
// 512 thr = 8 waves = 8 colquads (32 cols each, 2cg); each wave covers all
// 32 rows (2 rowgroups). Tile = 32 edges. Grid = 512 -> ALL blocks resident
// (2/CU): one block's compute covers the other's barrier/vmcnt drains.
// Regs/wave: bfrag 64 + acc 16 + sreg 16 + addr ~ <=128 (launch_bounds 512,4).
__global__ __launch_bounds__(512, 4) void k_edges(
    const float* __restrict__ instr, const float* __restrict__ dist,
    const float* __restrict__ eattrs, const unsigned short* __restrict__ Wbf,
    const float* __restrict__ wrs, const int* __restrict__ ebidx,
    const int* __restrict__ eidx, float* __restrict__ rel_logits)
{
    __shared__ char Al[2][16384];
    __shared__ float part[8][32];
    __shared__ int ebs[2][32];
    __shared__ int dsts[2][32];
    __shared__ float dscs[2][32];

    int tid = threadIdx.x;
    int lane = tid & 63;
    int cq = tid >> 6;          // wave = colquad 0..7
    int l15 = lane & 15;
    int q = lane >> 4;

    // persistent B fragments: this wave's 2x16-col slice of W_edge
    s16x8 bfrag[2][8];
#pragma unroll
    for (int cg = 0; cg < 2; ++cg)
#pragma unroll
        for (int kk = 0; kk < 8; ++kk)
            bfrag[cg][kk] = *(const s16x8*)(Wbf + (size_t)(cq * 32 + cg * 16 + l15) * ND + kk * 32 + q * 8);
    float wv0 = wrs[cq * 32 + l15];
    float wv1 = wrs[cq * 32 + 16 + l15];

    const int STRIDE = 512 * 32;
    int e0 = blockIdx.x * 32;
    f32x4 sreg[4];
    int mb = 0, md = 0; float ms = 0.f;
    stage_load(sreg, eattrs + (size_t)e0 * ND, tid,
               [&](int r) { return e0 + r < NE; });
    if (tid < 32) {
        int e = e0 + tid;
        if (e < NE) { mb = ebidx[e]; md = eidx[NE + e]; ms = dist[eidx[e]]; }
    }
    stage_write(Al[0], sreg, tid);
    if (tid < 32) { ebs[0][tid] = mb; dsts[0][tid] = md; dscs[0][tid] = ms; }
    __syncthreads();

    int cur = 0;
    while (true) {
        int e0n = e0 + STRIDE;
        bool hn = e0n < NE;
        if (hn) {   // issue next tile's loads early (hide under compute)
            stage_load(sreg, eattrs + (size_t)e0n * ND, tid,
                       [&](int r) { return e0n + r < NE; });
            if (tid < 32) {
                int e = e0n + tid;
                if (e < NE) { mb = ebidx[e]; md = eidx[NE + e]; ms = dist[eidx[e]]; }
                else { mb = 0; md = 0; ms = 0.f; }
            }
        }

        // ---- MFMA on Al[cur]: 2 rowgroups x 8 k-steps x 2 colgroups ----
        f32x4 acc[2][2] = {};
#pragma unroll
        for (int rg = 0; rg < 2; ++rg) {
            int arow = rg * 16 + l15;
#pragma unroll
            for (int kk = 0; kk < 8; ++kk) {
                s16x8 a = *(const s16x8*)(Al[cur] + swz(arow, kk * 64 + q * 16));
                acc[rg][0] = __builtin_amdgcn_mfma_f32_16x16x32_bf16(a, bfrag[0][kk], acc[rg][0], 0, 0, 0);
                acc[rg][1] = __builtin_amdgcn_mfma_f32_16x16x32_bf16(a, bfrag[1][kk], acc[rg][1], 0, 0, 0);
            }
        }

        // ---- epilogue: 32-col partial logit per edge via DPP rowsum ----
#pragma unroll
        for (int rg = 0; rg < 2; ++rg)
#pragma unroll
            for (int reg = 0; reg < 4; ++reg) {
                int rl = rg * 16 + 4 * q + reg;
                const float* irow = instr + (size_t)ebs[cur][rl] * ND;
                float x0 = irow[cq * 32 + l15] * acc[rg][0][reg];
                float x1 = irow[cq * 32 + 16 + l15] * acc[rg][1][reg];
                float p = rowsum16(wv0 * eluf(x0) + wv1 * eluf(x1));
                if (l15 == 0) part[cq][rl] = p;
            }
        __syncthreads();

        if (tid < 32 && e0 + tid < NE) {
            float s = 0.f;
#pragma unroll
            for (int w = 0; w < 8; ++w) s += part[w][tid];
            atomicAdd(&rel_logits[dsts[cur][tid]], dscs[cur][tid] * s);
        }
        if (hn) {
            stage_write(Al[cur ^ 1], sreg, tid);
            if (tid < 32) { ebs[cur ^ 1][tid] = mb; dsts[cur ^ 1][tid] = md; dscs[cur ^ 1][tid] = ms; }
        }
        __syncthreads();
        if (!hn) break;
        cur ^= 1; e0 = e0n;
    }
}

// ---------------- node kernel (same template, plain store) ----------------
// grid = NB*4: (b = idx>>2, qb = idx&3), 32-node tiles stride 4.
__global__ __launch_bounds__(512, 4) void k_nodes(
    const float* __restrict__ instr, const unsigned short* __restrict__ Weff,
    const float* __restrict__ attrs, const float* __restrict__ wns,
    const int* __restrict__ starts, float* __restrict__ state_logits)
{
    __shared__ char Al[2][16384];
    __shared__ float part[8][32];

    int b = blockIdx.x >> 2;
    int qb = blockIdx.x & 3;
    int s0 = starts[b], s1 = starts[b + 1];
    int nt = (s1 - s0 + 31) >> 5;
    if (qb >= nt) return;

    int tid = threadIdx.x;
    int lane = tid & 63;
    int cq = tid >> 6;
    int l15 = lane & 15;
    int q = lane >> 4;

    const unsigned short* Wb = Weff + (size_t)b * ND * ND;
    s16x8 bfrag[2][8];
#pragma unroll
    for (int cg = 0; cg < 2; ++cg)
#pragma unroll
        for (int kk = 0; kk < 8; ++kk)
            bfrag[cg][kk] = *(const s16x8*)(Wb + (size_t)(cq * 32 + cg * 16 + l15) * ND + kk * 32 + q * 8);
    float iv0 = instr[b * ND + cq * 32 + l15];
    float iv1 = instr[b * ND + cq * 32 + 16 + l15];
    float wv0 = wns[cq * 32 + l15];
    float wv1 = wns[cq * 32 + 16 + l15];

    int ti = qb;
    f32x4 sreg[4];
    {
        int node0 = s0 + ti * 32;
        stage_load(sreg, attrs + (size_t)node0 * ND, tid,
                   [&](int r) { return node0 + r < s1; });
        stage_write(Al[0], sreg, tid);
    }
    __syncthreads();

    int cur = 0;
    while (true) {
        int node0 = s0 + ti * 32;
        int tin = ti + 4;
        bool hn = tin < nt;
        if (hn) {
            int n0n = s0 + tin * 32;
            stage_load(sreg, attrs + (size_t)n0n * ND, tid,
                       [&](int r) { return n0n + r < s1; });
        }

        f32x4 acc[2][2] = {};
#pragma unroll
        for (int rg = 0; rg < 2; ++rg) {
            int arow = rg * 16 + l15;
#pragma unroll
            for (int kk = 0; kk < 8; ++kk) {
                s16x8 a = *(const s16x8*)(Al[cur] + swz(arow, kk * 64 + q * 16));
                acc[rg][0] = __builtin_amdgcn_mfma_f32_16x16x32_bf16(a, bfrag[0][kk], acc[rg][0], 0, 0, 0);
                acc[rg][1] = __builtin_amdgcn_mfma_f32_16x16x32_bf16(a, bfrag[1][kk], acc[rg][1], 0, 0, 0);
            }
        }

#pragma unroll
        for (int rg = 0; rg < 2; ++rg)
#pragma unroll
            for (int reg = 0; reg < 4; ++reg) {
                int rl = rg * 16 + 4 * q + reg;
                float p = rowsum16(wv0 * eluf(iv0 * acc[rg][0][reg])
                                 + wv1 * eluf(iv1 * acc[rg][1][reg]));
                if (l15 == 0) part[cq][rl] = p;
            }
        __syncthreads();

        if (tid < 32) {
            int node = node0 + tid;
            if (node < s1) {
                float s = 0.f;
#pragma unroll
                for (int w = 0; w < 8; ++w) s += part[w][tid];
                state_logits[node] = s;
            }
        }
        if (hn) stage_write(Al[cur ^ 1], sreg, tid);
        __syncthreads();
        if (!hn) break;
        cur ^= 1; ti = tin;
    }
}

// ---------------- per-graph softmaxes + final mix -------------------------
__global__ __launch_bounds__(256) void k_softmax_mix(
    const float* __restrict__ state_l, const float* __restrict__ rel_l,
    const int* __restrict__ starts, const float* __restrict__ relsim,
    float* __restrict__ out)
{
    __shared__ float wms[4], wmr[4], wss[4], wsr[4];
    int b = blockIdx.x;
    int s0 = starts[b], s1 = starts[b + 1];
    if (s1 <= s0) return;
    int tid = threadIdx.x, lane = tid & 63, wave = tid >> 6;

    float ms = -3.4e38f, mr = -3.4e38f;
    for (int n = s0 + tid; n < s1; n += 256) {
        ms = fmaxf(ms, state_l[n]);
        mr = fmaxf(mr, rel_l[n]);
    }
#pragma unroll
    for (int m = 1; m < 64; m <<= 1) {
        ms = fmaxf(ms, __shfl_xor(ms, m, 64));
        mr = fmaxf(mr, __shfl_xor(mr, m, 64));
    }
    if (lane == 0) { wms[wave] = ms; wmr[wave] = mr; }
    __syncthreads();
    ms = fmaxf(fmaxf(wms[0], wms[1]), fmaxf(wms[2], wms[3]));
    mr = fmaxf(fmaxf(wmr[0], wmr[1]), fmaxf(wmr[2], wmr[3]));

    float ss = 0.f, sr = 0.f;
    for (int n = s0 + tid; n < s1; n += 256) {
        ss += __expf(state_l[n] - ms);
        sr += __expf(rel_l[n] - mr);
    }
#pragma unroll
    for (int m = 1; m < 64; m <<= 1) {
        ss += __shfl_xor(ss, m, 64);
        sr += __shfl_xor(sr, m, 64);
    }
    if (lane == 0) { wss[wave] = ss; wsr[wave] = sr; }
    __syncthreads();
    ss = wss[0] + wss[1] + wss[2] + wss[3];
    sr = wsr[0] + wsr[1] + wsr[2] + wsr[3];

    float rb = relsim[b];
    float iss = 1.f / ss, isr = 1.f / sr;
    for (int n = s0 + tid; n < s1; n += 256) {
        out[n] = rb * __expf(rel_l[n] - mr) * isr
               + (1.f - rb) * __expf(state_l[n] - ms) * iss;
    }
}

extern "C" void kernel_launch(void* const* d_in, const int* in_sizes, int n_in,
                              void* d_out, int out_size, void* d_ws, size_t ws_size,
                              hipStream_t stream) {
    const float* instr  = (const float*)d_in[0];
    const float* dist   = (const float*)d_in[1];
    const float* sim    = (const float*)d_in[2];
    const float* relsim = (const float*)d_in[3];
    const float* nattr  = (const float*)d_in[4];
    const float* eattr  = (const float*)d_in[5];
    const float* Wp     = (const float*)d_in[6];
    const float* We     = (const float*)d_in[7];
    const float* wns    = (const float*)d_in[8];
    const float* wrs    = (const float*)d_in[9];
    const int* nidx     = (const int*)d_in[10];
    const int* ebidx    = (const int*)d_in[11];
    const int* eidx     = (const int*)d_in[12];
    float* out = (float*)d_out;

    char* ws = (char*)d_ws;
    float* rel_logits   = (float*)ws;                      // NN f @ 0
    float* state_logits = rel_logits + NN;                 // NN f @ 200000
    int* starts         = (int*)(ws + 400000);             // B+1 ints
    unsigned short* Wbf = (unsigned short*)(ws + 400640);  // 256*256 bf16
    unsigned short* Weff= (unsigned short*)(ws + 532480);  // 128*256*256 bf16 (16MB)

    k_wedge_bf16<<<64, 256, 0, stream>>>(We, Wbf);
    k_weff<<<dim3(32, 8), 256, 0, stream>>>(sim, Wp, Weff);
    k_starts<<<(NN + 255) / 256, 256, 0, stream>>>(nidx, starts, rel_logits);
    k_edges<<<512, 512, 0, stream>>>(instr, dist, eattr, Wbf, wrs,
                                     ebidx, eidx, rel_logits);
    k_nodes<<<NB * 4, 512, 0, stream>>>(instr, Weff, nattr, wns, starts,
                                        state_logits);
    k_softmax_mix<<<NB, 256, 0, stream>>>(state_logits, rel_logits, starts,
                                          relsim, out);
}